// Round 10
// baseline (194.099 us; speedup 1.0000x reference)
//
#include <hip/hip_runtime.h>
#include <hip/hip_fp16.h>
#include <cmath>

#define DIM 192
#define V (DIM * DIM * DIM)          // 7,077,888
#define V4 (V / 4)                   // 1,769,472 float4s
#define ROW4 (DIM / 4)               // 48 float4 per row
#define SLAB4 (ROW4 * DIM)           // 9216 float4 per z-slice
#define NSLOT 64                     // hashed atomic slots per statistic
#define ZB 8                         // z-outputs per thread in zpass
#define TY 16                        // y-rows per yx tile
#define YXB (DIM * (DIM / TY))       // 2304 blocks per sigma-pair

struct ZW { float w10[13], w15[13], w20[13], w30[13]; };
struct W2 { float wA[13], wB[13]; };

__device__ inline void fma4(float4& a, float w, const float4& v) {
    a.x += w * v.x; a.y += w * v.y; a.z += w * v.z; a.w += w * v.w;
}

// bijective XCD-aware swizzle (requires gridDim.x % 8 == 0)
__device__ inline int xcd_swz() {
    int b = blockIdx.x;
    return (b & 7) * (gridDim.x >> 3) + (b >> 3);
}

// ---- fp16 pack/unpack (4 values in a uint2) --------------------------------
__device__ inline uint2 pack_h4(float4 v) {
    __half2 lo = __floats2half2_rn(v.x, v.y);
    __half2 hi = __floats2half2_rn(v.z, v.w);
    uint2 r;
    r.x = *(unsigned int*)&lo;
    r.y = *(unsigned int*)&hi;
    return r;
}
__device__ inline float4 unpack_h4(uint2 p) {
    __half2 lo = *(__half2*)&p.x;
    __half2 hi = *(__half2*)&p.y;
    float2 a = __half22float2(lo), b = __half22float2(hi);
    return make_float4(a.x, a.y, b.x, b.y);
}
__device__ inline float4 ld4(const float4* p, int i) { return p[i]; }
__device__ inline float4 ld4(const uint2*  p, int i) { return unpack_h4(p[i]); }
__device__ inline void   st4(float4* p, int i, float4 v) { p[i] = v; }
__device__ inline void   st4(uint2*  p, int i, float4 v) { p[i] = pack_h4(v); }

// block-wide (256 thr) reduce of (s, s2) -> hashed-slot atomicAdd
__device__ inline void block_reduce_slot2(float s, float s2,
                                          double* slots0, double* slots1) {
    __shared__ float ws[4], ws2[4];
    __syncthreads();                       // protect reuse across calls
    for (int m = 1; m < 64; m <<= 1) {
        s  += __shfl_xor(s,  m, 64);
        s2 += __shfl_xor(s2, m, 64);
    }
    int wid = threadIdx.x >> 6, lane = threadIdx.x & 63;
    if (lane == 0) { ws[wid] = s; ws2[wid] = s2; }
    __syncthreads();
    if (threadIdx.x == 0) {
        int slot = blockIdx.x & (NSLOT - 1);
        atomicAdd(&slots0[slot], (double)(ws[0] + ws[1] + ws[2] + ws[3]));
        atomicAdd(&slots1[slot], (double)(ws2[0] + ws2[1] + ws2[2] + ws2[3]));
    }
}

// fold NSLOT hashed slots for stats [0, 12) into LDS fin[0..12)
__device__ inline void fold_slots12(const double* __restrict__ slots,
                                    double* fin) {
    int w = threadIdx.x >> 6, lane = threadIdx.x & 63;
    for (int t = w; t < 12; t += 4) {
        double s = slots[t * NSLOT + lane];          // NSLOT == 64
        for (int m = 1; m < 64; m <<= 1) s += __shfl_xor(s, m, 64);
        if (lane == 0) fin[t] = s;
    }
    __syncthreads();
}

__device__ inline void mean_inv2(double s, double s2, float& m, float& inv) {
    double mean = s / (double)V;
    double var  = (s2 - s * s / (double)V) / (double)(V - 1);
    m   = (float)mean;
    inv = (float)(1.0 / (sqrt(var) + 1e-8));
}

// ---- fused z-pass, 4 sigmas, ZB z-outputs per thread + ch0 stats -----------
__global__ __launch_bounds__(256) void zpass4(const float4* __restrict__ raw,
        float4* __restrict__ g10z, uint2* __restrict__ g15z,
        uint2* __restrict__ g20z, uint2* __restrict__ g30z,
        ZW zw, double* __restrict__ slots) {
    int tid = xcd_swz() * 256 + threadIdx.x;       // [0, V4/ZB)
    int x4 = tid % ROW4;
    int y  = (tid / ROW4) % DIM;
    int zg = tid / (ROW4 * DIM);
    int z0 = zg * ZB;
    int base = y * ROW4 + x4;
    float4 a10[ZB], a15[ZB], a20[ZB], a30[ZB];
#pragma unroll
    for (int k = 0; k < ZB; ++k) {
        a10[k] = make_float4(0,0,0,0); a15[k] = make_float4(0,0,0,0);
        a20[k] = make_float4(0,0,0,0); a30[k] = make_float4(0,0,0,0);
    }
    float s = 0.f, s2 = 0.f;
#pragma unroll
    for (int j = 0; j < ZB + 12; ++j) {            // ZB+12 taps cover ZB windows
        int zz = z0 + j - 6;
        if (zz >= 0 && zz < DIM) {
            float4 v = raw[zz * SLAB4 + base];
#pragma unroll
            for (int k = 0; k < ZB; ++k) {
                int w = j - k;                      // compile-time per (j,k)
                if (w >= 0 && w <= 12) {
                    fma4(a10[k], zw.w10[w], v);
                    fma4(a15[k], zw.w15[w], v);
                    fma4(a20[k], zw.w20[w], v);
                    fma4(a30[k], zw.w30[w], v);
                }
            }
            if (j >= 6 && j < 6 + ZB) {            // v is a center value
                s  += v.x + v.y + v.z + v.w;
                s2 += v.x*v.x + v.y*v.y + v.z*v.z + v.w*v.w;
            }
        }
    }
#pragma unroll
    for (int k = 0; k < ZB; ++k) {
        int idx = (z0 + k) * SLAB4 + base;
        g10z[idx] = a10[k];
        g15z[idx] = pack_h4(a15[k]);
        g20z[idx] = pack_h4(a20[k]);
        g30z[idx] = pack_h4(a30[k]);
    }
    block_reduce_slot2(s, s2, slots + 0 * NSLOT, slots + 1 * NSLOT);
}

// ---- y+x tile body: stage z-volumes in LDS, y-conv from LDS, x-conv --------
template <int KYA, int KYB, int KXA, int KXB, bool WRITE_G, bool OUT_H,
          typename TA, typename TB>
__device__ void yx_tile(int tile, const TA* __restrict__ inA,
        const TB* __restrict__ inB, float4* __restrict__ outG,
        float4* __restrict__ outCf, uint2* __restrict__ outCh,
        char* stage, float4* yA4, float4* yB4,
        const W2& wy, const W2& wx, double* s0, double* s1) {
    constexpr int NF4 = TY * ROW4;            // 768 float4 per tile
    constexpr int HYA = KYA / 2, HYB = KYB / 2;   // HYB >= HYA always
    constexpr int SR  = TY + 2 * HYB;         // staged rows
    constexpr int HXA = KXA / 2, HXB = KXB / 2;
    constexpr int WQA = (HXA + 3) / 4;
    constexpr int WQB = (HXB + 3) / 4;
    TA* sA = (TA*)stage;                       // SR*ROW4 elems
    TB* sB = (TB*)(stage + sizeof(TA) * SR * ROW4);
    int z  = tile / (DIM / TY);
    int y0 = (tile % (DIM / TY)) * TY;
    const int slab = z * SLAB4;
    // ---- stage input rows [y0-HYB, y0+TY-1+HYB], zero-padded ---------------
    for (int e = threadIdx.x; e < SR * ROW4; e += 256) {
        int r  = e / ROW4;
        int x4 = e % ROW4;
        int yy = y0 - HYB + r;
        bool ok = (yy >= 0 && yy < DIM);
        int gi = slab + yy * ROW4 + x4;
        if (ok) { sA[e] = inA[gi]; sB[e] = inB[gi]; }
        else {
            st4(sA, e, make_float4(0,0,0,0));
            st4(sB, e, make_float4(0,0,0,0));
        }
    }
    __syncthreads();
    // ---- y-convolution from LDS into yA4/yB4 -------------------------------
    for (int e = threadIdx.x; e < NF4; e += 256) {
        int r  = e / ROW4;
        int x4 = e % ROW4;
        float4 a = {0,0,0,0}, b = {0,0,0,0};
#pragma unroll
        for (int t = 0; t < KYA; ++t)
            fma4(a, wy.wA[t], ld4(sA, (r + t + HYB - HYA) * ROW4 + x4));
#pragma unroll
        for (int t = 0; t < KYB; ++t)
            fma4(b, wy.wB[t], ld4(sB, (r + t) * ROW4 + x4));
        yA4[e] = a;
        yB4[e] = b;
    }
    __syncthreads();
    // ---- x-convolution via register windows --------------------------------
    float s = 0.f, s2 = 0.f;
    for (int e = threadIdx.x; e < NF4; e += 256) {
        int r = e / ROW4, x4 = e % ROW4;
        const float4* rowA = yA4 + r * ROW4;
        const float4* rowB = yB4 + r * ROW4;
        float wa[4 * (2 * WQA + 1)], wb[4 * (2 * WQB + 1)];
#pragma unroll
        for (int q = -WQA; q <= WQA; ++q) {
            float4 v = ((unsigned)(x4 + q) < (unsigned)ROW4) ? rowA[x4 + q]
                                                             : make_float4(0,0,0,0);
            int b0 = 4 * (q + WQA);
            wa[b0] = v.x; wa[b0 + 1] = v.y; wa[b0 + 2] = v.z; wa[b0 + 3] = v.w;
        }
#pragma unroll
        for (int q = -WQB; q <= WQB; ++q) {
            float4 v = ((unsigned)(x4 + q) < (unsigned)ROW4) ? rowB[x4 + q]
                                                             : make_float4(0,0,0,0);
            int b0 = 4 * (q + WQB);
            wb[b0] = v.x; wb[b0 + 1] = v.y; wb[b0 + 2] = v.z; wb[b0 + 3] = v.w;
        }
        float g[4], cv[4];
#pragma unroll
        for (int j = 0; j < 4; ++j) {
            float ca = 0.f, cb = 0.f;
#pragma unroll
            for (int t = 0; t < KXA; ++t) ca += wx.wA[t] * wa[4 * WQA + j + t - HXA];
#pragma unroll
            for (int t = 0; t < KXB; ++t) cb += wx.wB[t] * wb[4 * WQB + j + t - HXB];
            g[j] = ca;
            cv[j] = ca - cb;
            s += cv[j]; s2 += cv[j] * cv[j];
        }
        int gi = slab + (y0 + r) * ROW4 + x4;
        if constexpr (WRITE_G) outG[gi] = make_float4(g[0], g[1], g[2], g[3]);
        if constexpr (OUT_H)   outCh[gi] = pack_h4(make_float4(cv[0], cv[1], cv[2], cv[3]));
        else                   outCf[gi] = make_float4(cv[0], cv[1], cv[2], cv[3]);
    }
    block_reduce_slot2(s, s2, s0, s1);
}

// stage buffer: max(pairA: 22*48*(16+8)=25344, pairB: 28*48*(8+8)=21504)
#define STAGE_BYTES 25344

// ---- merged y+x kernel: both sigma pairs in one dispatch -------------------
__global__ __launch_bounds__(256) void yx_both(
        const float4* __restrict__ g10z, const uint2* __restrict__ g15z,
        const uint2* __restrict__ g20z, const uint2* __restrict__ g30z,
        float4* __restrict__ o0, float4* __restrict__ o1, float4* __restrict__ o2,
        uint2* __restrict__ ch1h, uint2* __restrict__ ch2h, int useH,
        W2 wyA, W2 wxA, W2 wyB, W2 wxB, double* __restrict__ slots) {
    __shared__ __align__(16) char stage[STAGE_BYTES];
    __shared__ float4 yA4[TY * ROW4], yB4[TY * ROW4];
    int bid = xcd_swz();
    if (bid < YXB) {
        if (useH)
            yx_tile<5, 7, 5, 7, true, true>(bid, g10z, g15z, o0, (float4*)nullptr,
                ch1h, stage, yA4, yB4, wyA, wxA, slots + 2 * NSLOT, slots + 3 * NSLOT);
        else
            yx_tile<5, 7, 5, 7, true, false>(bid, g10z, g15z, o0, o1,
                (uint2*)nullptr, stage, yA4, yB4, wyA, wxA,
                slots + 2 * NSLOT, slots + 3 * NSLOT);
    } else {
        bid -= YXB;
        if (useH)
            yx_tile<9, 13, 9, 13, false, true>(bid, g20z, g30z, (float4*)nullptr,
                (float4*)nullptr, ch2h, stage, yA4, yB4, wyB, wxB,
                slots + 4 * NSLOT, slots + 5 * NSLOT);
        else
            yx_tile<9, 13, 9, 13, false, false>(bid, g20z, g30z, (float4*)nullptr,
                o2, (uint2*)nullptr, stage, yA4, yB4, wyB, wxB,
                slots + 4 * NSLOT, slots + 5 * NSLOT);
    }
}

// ---- shared derivative math -------------------------------------------------
__device__ inline void deriv_point(const float4* g4, const float* g, int i,
                                   float o3[4], float o4[4], float o5[4]) {
    int x4 = i % ROW4;
    int y  = (i / ROW4) % DIM;
    int z  = i / SLAB4;
    const float4 zero = {0,0,0,0};
    float4 c  = g4[i];
    float4 zm = (z > 0)       ? g4[i - SLAB4] : zero;
    float4 zp = (z < DIM - 1) ? g4[i + SLAB4] : zero;
    float4 ym = (y > 0)       ? g4[i - ROW4]  : zero;
    float4 yp = (y < DIM - 1) ? g4[i + ROW4]  : zero;
    float lf = (x4 > 0)        ? g[4 * i - 1] : 0.f;
    float rt = (x4 < ROW4 - 1) ? g[4 * i + 4] : 0.f;
    float xm[4] = { lf, c.x, c.y, c.z };
    float xp[4] = { c.y, c.z, c.w, rt };
    float cc[4] = { c.x, c.y, c.z, c.w };
    float zmv[4] = { zm.x, zm.y, zm.z, zm.w };
    float zpv[4] = { zp.x, zp.y, zp.z, zp.w };
    float ymv[4] = { ym.x, ym.y, ym.z, ym.w };
    float ypv[4] = { yp.x, yp.y, yp.z, yp.w };
#pragma unroll
    for (int j = 0; j < 4; ++j) {
        float gx = 0.5f * (xp[j] - xm[j]);
        float gy = 0.5f * (ypv[j] - ymv[j]);
        float gz = 0.5f * (zpv[j] - zmv[j]);
        o3[j] = xm[j] + xp[j] + ymv[j] + ypv[j] + zmv[j] + zpv[j] - 6.f * cc[j];
        o4[j] = sqrtf(gx * gx + gy * gy + gz * gz + 1e-8f);
        o5[j] = fminf(fabsf(gy) / (fabsf(gx) + 1e-3f), 20.f);
    }
}

// ---- ch3/4/5 statistics only (no writes) -----------------------------------
__global__ __launch_bounds__(256) void deriv_stats(const float4* __restrict__ g4,
        const float* __restrict__ g, double* __restrict__ slots) {
    int i = xcd_swz() * 256 + threadIdx.x;
    float o3[4], o4[4], o5[4];
    deriv_point(g4, g, i, o3, o4, o5);
    float s3 = 0, q3 = 0, s4 = 0, q4 = 0, s5 = 0, q5 = 0;
#pragma unroll
    for (int j = 0; j < 4; ++j) {
        s3 += o3[j]; q3 += o3[j] * o3[j];
        s4 += o4[j]; q4 += o4[j] * o4[j];
        s5 += o5[j]; q5 += o5[j] * o5[j];
    }
    block_reduce_slot2(s3, q3, slots + 6 * NSLOT,  slots + 7 * NSLOT);
    block_reduce_slot2(s4, q4, slots + 8 * NSLOT,  slots + 9 * NSLOT);
    block_reduce_slot2(s5, q5, slots + 10 * NSLOT, slots + 11 * NSLOT);
}

// ---- merged normalize: all 6 channels in one dispatch ----------------------
// blocks [0, V4/256): deriv path -> normalized ch3/4/5
// blocks [V4/256, V4/256 + 3*V4/256): ch0 (raw), ch1, ch2
__global__ __launch_bounds__(256) void norm_all(const float4* __restrict__ raw,
        const float4* __restrict__ g4, const float* __restrict__ g,
        const uint2* __restrict__ ch1h, const uint2* __restrict__ ch2h,
        float4* __restrict__ out, const double* __restrict__ slots, int useH) {
    __shared__ double fin[12];
    fold_slots12(slots, fin);
    const int nd = V4 / 256;                 // 6912 deriv blocks
    if ((int)blockIdx.x < nd) {
        int b = blockIdx.x;
        int bs = (b & 7) * (nd >> 3) + (b >> 3);   // XCD swizzle within part
        int i = bs * 256 + threadIdx.x;
        float o3[4], o4[4], o5[4];
        deriv_point(g4, g, i, o3, o4, o5);
        float m3, i3, m4, i4, m5, i5;
        mean_inv2(fin[6],  fin[7],  m3, i3);
        mean_inv2(fin[8],  fin[9],  m4, i4);
        mean_inv2(fin[10], fin[11], m5, i5);
        out[(size_t)3 * V4 + i] =
            make_float4((o3[0]-m3)*i3, (o3[1]-m3)*i3, (o3[2]-m3)*i3, (o3[3]-m3)*i3);
        out[(size_t)4 * V4 + i] =
            make_float4((o4[0]-m4)*i4, (o4[1]-m4)*i4, (o4[2]-m4)*i4, (o4[3]-m4)*i4);
        out[(size_t)5 * V4 + i] =
            make_float4((o5[0]-m5)*i5, (o5[1]-m5)*i5, (o5[2]-m5)*i5, (o5[3]-m5)*i5);
    } else {
        int i = ((int)blockIdx.x - nd) * 256 + threadIdx.x;   // < 3*V4
        int c = i / V4;
        int ii = i - c * V4;
        float m, inv;
        mean_inv2(fin[2 * c], fin[2 * c + 1], m, inv);
        float4 v;
        if (c == 0)     v = raw[ii];
        else if (useH)  v = unpack_h4((c == 1 ? ch1h : ch2h)[ii]);
        else            v = out[(size_t)c * V4 + ii];
        v.x = (v.x - m) * inv;
        v.y = (v.y - m) * inv;
        v.z = (v.z - m) * inv;
        v.w = (v.w - m) * inv;
        out[(size_t)c * V4 + ii] = v;
    }
}

// ---- host: Gaussian weights ------------------------------------------------
static void gauss_w(double sigma, float* w13, int center) {
    int ks = (int)(4.0 * sigma + 1.0);
    if (ks % 2 == 0) ks++;
    double tmp[13], sum = 0.0;
    for (int i = 0; i < ks; ++i) {
        double x = (double)(i - ks / 2);
        tmp[i] = exp(-0.5 * x * x / (sigma * sigma));
        sum += tmp[i];
    }
    for (int i = 0; i < 13; ++i) w13[i] = 0.f;
    int h = ks / 2;
    for (int i = 0; i < ks; ++i) w13[center + (i - h)] = (float)(tmp[i] / sum);
}

extern "C" void kernel_launch(void* const* d_in, const int* in_sizes, int n_in,
                              void* d_out, int out_size, void* d_ws, size_t ws_size,
                              hipStream_t stream) {
    const float* raw = (const float*)d_in[0];
    float* out = (float*)d_out;
    float* o[6];
    for (int c = 0; c < 6; ++c) o[c] = out + (size_t)c * V;
    double* slots = (double*)d_ws;                  // 12 * 64 doubles

    // optional fp16 staging of pre-norm ch1/ch2 in workspace
    size_t stage_off = 8192;
    size_t stage_need = stage_off + 2 * (size_t)V4 * sizeof(uint2);  // ~28.3 MB
    int useH = (ws_size >= stage_need) ? 1 : 0;
    uint2* ch1h = (uint2*)((char*)d_ws + stage_off);
    uint2* ch2h = ch1h + V4;

    hipMemsetAsync(d_ws, 0, 12 * NSLOT * sizeof(double), stream);

    // weights (each centered at its own KS/2)
    ZW zw;
    gauss_w(1.0, zw.w10, 6); gauss_w(1.5, zw.w15, 6);
    gauss_w(2.0, zw.w20, 6); gauss_w(3.0, zw.w30, 6);
    W2 wyA; gauss_w(1.0, wyA.wA, 2);  gauss_w(1.5, wyA.wB, 3);   // KY 5, 7
    W2 wxA; gauss_w(1.0, wxA.wA, 2);  gauss_w(1.5, wxA.wB, 3);   // KX 5, 7
    W2 wyB; gauss_w(2.0, wyB.wA, 4);  gauss_w(3.0, wyB.wB, 6);   // KY 9, 13
    W2 wxB; gauss_w(2.0, wxB.wA, 4);  gauss_w(3.0, wxB.wB, 6);   // KX 9, 13

    const float4* raw4 = (const float4*)raw;
    dim3 blk(256);
    int g4blocks = V4 / 256;                 // 6912
    int zblocks  = V4 / (ZB * 256);          // 864

    // intermediate placement:
    //   g10z (fp32)  -> o5
    //   g15z (fp16)  -> o3 lower half
    //   g20z (fp16)  -> o3 upper half
    //   g30z (fp16)  -> o4 lower half
    float4* g10z = (float4*)o[5];
    uint2*  g15z = (uint2*)o[3];
    uint2*  g20z = (uint2*)o[3] + V4;
    uint2*  g30z = (uint2*)o[4];

    // z-pass (all sigmas, ZB z per thread) + ch0 stats
    zpass4<<<zblocks, blk, 0, stream>>>(raw4, g10z, g15z, g20z, g30z, zw, slots);
    // merged y+x for both sigma pairs (LDS-staged y-conv)
    yx_both<<<2 * YXB, blk, 0, stream>>>(g10z, g15z, g20z, g30z,
        (float4*)o[0], (float4*)o[1], (float4*)o[2], ch1h, ch2h, useH,
        wyA, wxA, wyB, wxB, slots);
    // ch3/4/5 statistics from G10 (o0), no writes
    deriv_stats<<<g4blocks, blk, 0, stream>>>((const float4*)o[0], o[0], slots);
    // merged normalize of all 6 channels (deriv recompute inside)
    norm_all<<<g4blocks + (3 * V4) / 256, blk, 0, stream>>>(raw4,
        (const float4*)o[0], o[0], ch1h, ch2h, (float4*)out, slots, useH);
}

// Round 11
// 184.162 us; speedup vs baseline: 1.0540x; 1.0540x over previous
//
#include <hip/hip_runtime.h>
#include <hip/hip_fp16.h>
#include <cmath>

#define DIM 192
#define V (DIM * DIM * DIM)          // 7,077,888
#define V4 (V / 4)                   // 1,769,472 float4s
#define ROW4 (DIM / 4)               // 48 float4 per row
#define SLAB4 (ROW4 * DIM)           // 9216 float4 per z-slice
#define NSLOT 64                     // hashed atomic slots per statistic
#define ZB 4                         // z-outputs per thread in zpass
#define TY 16                        // y-rows per yx tile
#define YXB (DIM * (DIM / TY))       // 2304 blocks per sigma-pair

struct ZW { float w10[13], w15[13], w20[13], w30[13]; };
struct W2 { float wA[13], wB[13]; };

__device__ inline void fma4(float4& a, float w, const float4& v) {
    a.x += w * v.x; a.y += w * v.y; a.z += w * v.z; a.w += w * v.w;
}

// bijective XCD-aware swizzle (requires gridDim.x % 8 == 0)
__device__ inline int xcd_swz() {
    int b = blockIdx.x;
    return (b & 7) * (gridDim.x >> 3) + (b >> 3);
}

// ---- fp16 pack/unpack (4 values in a uint2) --------------------------------
__device__ inline uint2 pack_h4(float4 v) {
    __half2 lo = __floats2half2_rn(v.x, v.y);
    __half2 hi = __floats2half2_rn(v.z, v.w);
    uint2 r;
    r.x = *(unsigned int*)&lo;
    r.y = *(unsigned int*)&hi;
    return r;
}
__device__ inline float4 unpack_h4(uint2 p) {
    __half2 lo = *(__half2*)&p.x;
    __half2 hi = *(__half2*)&p.y;
    float2 a = __half22float2(lo), b = __half22float2(hi);
    return make_float4(a.x, a.y, b.x, b.y);
}
__device__ inline float4 ld4(const float4* p, int i) { return p[i]; }
__device__ inline float4 ld4(const uint2*  p, int i) { return unpack_h4(p[i]); }
__device__ inline void   st4(float4* p, int i, float4 v) { p[i] = v; }
__device__ inline void   st4(uint2*  p, int i, float4 v) { p[i] = pack_h4(v); }

// ---- zero the stat slots (replaces pathological graph-captured memset) -----
__global__ void zero_slots(double* __restrict__ slots) {
    int i = blockIdx.x * 256 + threadIdx.x;        // grid 3*256 = 768 doubles
    slots[i] = 0.0;
}

// block-wide (256 thr) reduce of (s, s2) -> hashed-slot atomicAdd
__device__ inline void block_reduce_slot2(float s, float s2,
                                          double* slots0, double* slots1) {
    __shared__ float ws[4], ws2[4];
    __syncthreads();                       // protect reuse across calls
    for (int m = 1; m < 64; m <<= 1) {
        s  += __shfl_xor(s,  m, 64);
        s2 += __shfl_xor(s2, m, 64);
    }
    int wid = threadIdx.x >> 6, lane = threadIdx.x & 63;
    if (lane == 0) { ws[wid] = s; ws2[wid] = s2; }
    __syncthreads();
    if (threadIdx.x == 0) {
        int slot = blockIdx.x & (NSLOT - 1);
        atomicAdd(&slots0[slot], (double)(ws[0] + ws[1] + ws[2] + ws[3]));
        atomicAdd(&slots1[slot], (double)(ws2[0] + ws2[1] + ws2[2] + ws2[3]));
    }
}

// fold NSLOT hashed slots for stats [base, base+n) into LDS fin[0..n)
__device__ inline void fold_slots(const double* __restrict__ slots, int base,
                                  int n, double* fin) {
    int w = threadIdx.x >> 6, lane = threadIdx.x & 63;
    for (int t = base + w; t < base + n; t += 4) {
        double s = slots[t * NSLOT + lane];          // NSLOT == 64
        for (int m = 1; m < 64; m <<= 1) s += __shfl_xor(s, m, 64);
        if (lane == 0) fin[t - base] = s;
    }
    __syncthreads();
}

__device__ inline void mean_inv2(double s, double s2, float& m, float& inv) {
    double mean = s / (double)V;
    double var  = (s2 - s * s / (double)V) / (double)(V - 1);
    m   = (float)mean;
    inv = (float)(1.0 / (sqrt(var) + 1e-8));
}

// ---- fused z-pass, 4 sigmas, ZB z-outputs per thread + ch0 stats -----------
__global__ __launch_bounds__(256) void zpass4(const float4* __restrict__ raw,
        float4* __restrict__ g10z, uint2* __restrict__ g15z,
        uint2* __restrict__ g20z, uint2* __restrict__ g30z,
        ZW zw, double* __restrict__ slots) {
    int tid = xcd_swz() * 256 + threadIdx.x;       // [0, V4/ZB)
    int x4 = tid % ROW4;
    int y  = (tid / ROW4) % DIM;
    int zg = tid / (ROW4 * DIM);
    int z0 = zg * ZB;
    int base = y * ROW4 + x4;
    float4 a10[ZB], a15[ZB], a20[ZB], a30[ZB];
#pragma unroll
    for (int k = 0; k < ZB; ++k) {
        a10[k] = make_float4(0,0,0,0); a15[k] = make_float4(0,0,0,0);
        a20[k] = make_float4(0,0,0,0); a30[k] = make_float4(0,0,0,0);
    }
    float s = 0.f, s2 = 0.f;
#pragma unroll
    for (int j = 0; j < ZB + 12; ++j) {            // 16 taps cover ZB windows
        int zz = z0 + j - 6;
        if (zz >= 0 && zz < DIM) {
            float4 v = raw[zz * SLAB4 + base];
#pragma unroll
            for (int k = 0; k < ZB; ++k) {
                int w = j - k;                      // compile-time per (j,k)
                if (w >= 0 && w <= 12) {
                    fma4(a10[k], zw.w10[w], v);
                    fma4(a15[k], zw.w15[w], v);
                    fma4(a20[k], zw.w20[w], v);
                    fma4(a30[k], zw.w30[w], v);
                }
            }
            if (j >= 6 && j < 6 + ZB) {            // v is a center value
                s  += v.x + v.y + v.z + v.w;
                s2 += v.x*v.x + v.y*v.y + v.z*v.z + v.w*v.w;
            }
        }
    }
#pragma unroll
    for (int k = 0; k < ZB; ++k) {
        int idx = (z0 + k) * SLAB4 + base;
        g10z[idx] = a10[k];
        g15z[idx] = pack_h4(a15[k]);
        g20z[idx] = pack_h4(a20[k]);
        g30z[idx] = pack_h4(a30[k]);
    }
    block_reduce_slot2(s, s2, slots + 0 * NSLOT, slots + 1 * NSLOT);
}

// ---- y+x tile body: stage z-volumes in LDS, y-conv from LDS, x-conv --------
template <int KYA, int KYB, int KXA, int KXB, bool WRITE_G, bool OUT_H,
          typename TA, typename TB>
__device__ void yx_tile(int tile, const TA* __restrict__ inA,
        const TB* __restrict__ inB, float4* __restrict__ outG,
        float4* __restrict__ outCf, uint2* __restrict__ outCh,
        char* stage, float4* yA4, float4* yB4,
        const W2& wy, const W2& wx, double* s0, double* s1) {
    constexpr int NF4 = TY * ROW4;            // 768 float4 per tile
    constexpr int HYA = KYA / 2, HYB = KYB / 2;   // HYB >= HYA always
    constexpr int SR  = TY + 2 * HYB;         // staged rows
    constexpr int HXA = KXA / 2, HXB = KXB / 2;
    constexpr int WQA = (HXA + 3) / 4;
    constexpr int WQB = (HXB + 3) / 4;
    TA* sA = (TA*)stage;                       // SR*ROW4 elems
    TB* sB = (TB*)(stage + sizeof(TA) * SR * ROW4);
    int z  = tile / (DIM / TY);
    int y0 = (tile % (DIM / TY)) * TY;
    const int slab = z * SLAB4;
    // ---- stage input rows [y0-HYB, y0+TY-1+HYB], zero-padded ---------------
    for (int e = threadIdx.x; e < SR * ROW4; e += 256) {
        int r  = e / ROW4;
        int x4 = e % ROW4;
        int yy = y0 - HYB + r;
        bool ok = (yy >= 0 && yy < DIM);
        int gi = slab + yy * ROW4 + x4;
        if (ok) { sA[e] = inA[gi]; sB[e] = inB[gi]; }
        else {
            st4(sA, e, make_float4(0,0,0,0));
            st4(sB, e, make_float4(0,0,0,0));
        }
    }
    __syncthreads();
    // ---- y-convolution from LDS into yA4/yB4 -------------------------------
    for (int e = threadIdx.x; e < NF4; e += 256) {
        int r  = e / ROW4;
        int x4 = e % ROW4;
        float4 a = {0,0,0,0}, b = {0,0,0,0};
#pragma unroll
        for (int t = 0; t < KYA; ++t)
            fma4(a, wy.wA[t], ld4(sA, (r + t + HYB - HYA) * ROW4 + x4));
#pragma unroll
        for (int t = 0; t < KYB; ++t)
            fma4(b, wy.wB[t], ld4(sB, (r + t) * ROW4 + x4));
        yA4[e] = a;
        yB4[e] = b;
    }
    __syncthreads();
    // ---- x-convolution via register windows --------------------------------
    float s = 0.f, s2 = 0.f;
    for (int e = threadIdx.x; e < NF4; e += 256) {
        int r = e / ROW4, x4 = e % ROW4;
        const float4* rowA = yA4 + r * ROW4;
        const float4* rowB = yB4 + r * ROW4;
        float wa[4 * (2 * WQA + 1)], wb[4 * (2 * WQB + 1)];
#pragma unroll
        for (int q = -WQA; q <= WQA; ++q) {
            float4 v = ((unsigned)(x4 + q) < (unsigned)ROW4) ? rowA[x4 + q]
                                                             : make_float4(0,0,0,0);
            int b0 = 4 * (q + WQA);
            wa[b0] = v.x; wa[b0 + 1] = v.y; wa[b0 + 2] = v.z; wa[b0 + 3] = v.w;
        }
#pragma unroll
        for (int q = -WQB; q <= WQB; ++q) {
            float4 v = ((unsigned)(x4 + q) < (unsigned)ROW4) ? rowB[x4 + q]
                                                             : make_float4(0,0,0,0);
            int b0 = 4 * (q + WQB);
            wb[b0] = v.x; wb[b0 + 1] = v.y; wb[b0 + 2] = v.z; wb[b0 + 3] = v.w;
        }
        float g[4], cv[4];
#pragma unroll
        for (int j = 0; j < 4; ++j) {
            float ca = 0.f, cb = 0.f;
#pragma unroll
            for (int t = 0; t < KXA; ++t) ca += wx.wA[t] * wa[4 * WQA + j + t - HXA];
#pragma unroll
            for (int t = 0; t < KXB; ++t) cb += wx.wB[t] * wb[4 * WQB + j + t - HXB];
            g[j] = ca;
            cv[j] = ca - cb;
            s += cv[j]; s2 += cv[j] * cv[j];
        }
        int gi = slab + (y0 + r) * ROW4 + x4;
        if constexpr (WRITE_G) outG[gi] = make_float4(g[0], g[1], g[2], g[3]);
        if constexpr (OUT_H)   outCh[gi] = pack_h4(make_float4(cv[0], cv[1], cv[2], cv[3]));
        else                   outCf[gi] = make_float4(cv[0], cv[1], cv[2], cv[3]);
    }
    block_reduce_slot2(s, s2, s0, s1);
}

// stage buffer: max(pairA: 22*48*(16+8)=25344, pairB: 28*48*(8+8)=21504)
#define STAGE_BYTES 25344

// ---- merged y+x kernel: both sigma pairs in one dispatch -------------------
__global__ __launch_bounds__(256) void yx_both(
        const float4* __restrict__ g10z, const uint2* __restrict__ g15z,
        const uint2* __restrict__ g20z, const uint2* __restrict__ g30z,
        float4* __restrict__ o0, float4* __restrict__ o1, float4* __restrict__ o2,
        uint2* __restrict__ ch1h, uint2* __restrict__ ch2h, int useH,
        W2 wyA, W2 wxA, W2 wyB, W2 wxB, double* __restrict__ slots) {
    __shared__ __align__(16) char stage[STAGE_BYTES];
    __shared__ float4 yA4[TY * ROW4], yB4[TY * ROW4];
    int bid = xcd_swz();
    if (bid < YXB) {
        if (useH)
            yx_tile<5, 7, 5, 7, true, true>(bid, g10z, g15z, o0, (float4*)nullptr,
                ch1h, stage, yA4, yB4, wyA, wxA, slots + 2 * NSLOT, slots + 3 * NSLOT);
        else
            yx_tile<5, 7, 5, 7, true, false>(bid, g10z, g15z, o0, o1,
                (uint2*)nullptr, stage, yA4, yB4, wyA, wxA,
                slots + 2 * NSLOT, slots + 3 * NSLOT);
    } else {
        bid -= YXB;
        if (useH)
            yx_tile<9, 13, 9, 13, false, true>(bid, g20z, g30z, (float4*)nullptr,
                (float4*)nullptr, ch2h, stage, yA4, yB4, wyB, wxB,
                slots + 4 * NSLOT, slots + 5 * NSLOT);
        else
            yx_tile<9, 13, 9, 13, false, false>(bid, g20z, g30z, (float4*)nullptr,
                o2, (uint2*)nullptr, stage, yA4, yB4, wyB, wxB,
                slots + 4 * NSLOT, slots + 5 * NSLOT);
    }
}

// ---- shared derivative math -------------------------------------------------
__device__ inline void deriv_point(const float4* g4, const float* g, int i,
                                   float o3[4], float o4[4], float o5[4]) {
    int x4 = i % ROW4;
    int y  = (i / ROW4) % DIM;
    int z  = i / SLAB4;
    const float4 zero = {0,0,0,0};
    float4 c  = g4[i];
    float4 zm = (z > 0)       ? g4[i - SLAB4] : zero;
    float4 zp = (z < DIM - 1) ? g4[i + SLAB4] : zero;
    float4 ym = (y > 0)       ? g4[i - ROW4]  : zero;
    float4 yp = (y < DIM - 1) ? g4[i + ROW4]  : zero;
    float lf = (x4 > 0)        ? g[4 * i - 1] : 0.f;
    float rt = (x4 < ROW4 - 1) ? g[4 * i + 4] : 0.f;
    float xm[4] = { lf, c.x, c.y, c.z };
    float xp[4] = { c.y, c.z, c.w, rt };
    float cc[4] = { c.x, c.y, c.z, c.w };
    float zmv[4] = { zm.x, zm.y, zm.z, zm.w };
    float zpv[4] = { zp.x, zp.y, zp.z, zp.w };
    float ymv[4] = { ym.x, ym.y, ym.z, ym.w };
    float ypv[4] = { yp.x, yp.y, yp.z, yp.w };
#pragma unroll
    for (int j = 0; j < 4; ++j) {
        float gx = 0.5f * (xp[j] - xm[j]);
        float gy = 0.5f * (ypv[j] - ymv[j]);
        float gz = 0.5f * (zpv[j] - zmv[j]);
        o3[j] = xm[j] + xp[j] + ymv[j] + ypv[j] + zmv[j] + zpv[j] - 6.f * cc[j];
        o4[j] = sqrtf(gx * gx + gy * gy + gz * gz + 1e-8f);
        o5[j] = fminf(fabsf(gy) / (fabsf(gx) + 1e-3f), 20.f);
    }
}

// ---- ch3/4/5 statistics only (no writes) -----------------------------------
__global__ __launch_bounds__(256) void deriv_stats(const float4* __restrict__ g4,
        const float* __restrict__ g, double* __restrict__ slots) {
    int i = xcd_swz() * 256 + threadIdx.x;
    float o3[4], o4[4], o5[4];
    deriv_point(g4, g, i, o3, o4, o5);
    float s3 = 0, q3 = 0, s4 = 0, q4 = 0, s5 = 0, q5 = 0;
#pragma unroll
    for (int j = 0; j < 4; ++j) {
        s3 += o3[j]; q3 += o3[j] * o3[j];
        s4 += o4[j]; q4 += o4[j] * o4[j];
        s5 += o5[j]; q5 += o5[j] * o5[j];
    }
    block_reduce_slot2(s3, q3, slots + 6 * NSLOT,  slots + 7 * NSLOT);
    block_reduce_slot2(s4, q4, slots + 8 * NSLOT,  slots + 9 * NSLOT);
    block_reduce_slot2(s5, q5, slots + 10 * NSLOT, slots + 11 * NSLOT);
}

// ---- recompute derivatives from G10 and write NORMALIZED ch3/4/5 -----------
__global__ __launch_bounds__(256) void norm_deriv(const float4* __restrict__ g4,
        const float* __restrict__ g, float4* __restrict__ c3,
        float4* __restrict__ c4o, float4* __restrict__ c5,
        const double* __restrict__ slots) {
    __shared__ double fin[6];
    fold_slots(slots, 6, 6, fin);
    int i = xcd_swz() * 256 + threadIdx.x;
    float o3[4], o4[4], o5[4];
    deriv_point(g4, g, i, o3, o4, o5);
    float m3, i3, m4, i4, m5, i5;
    mean_inv2(fin[0], fin[1], m3, i3);
    mean_inv2(fin[2], fin[3], m4, i4);
    mean_inv2(fin[4], fin[5], m5, i5);
    c3[i]  = make_float4((o3[0]-m3)*i3, (o3[1]-m3)*i3, (o3[2]-m3)*i3, (o3[3]-m3)*i3);
    c4o[i] = make_float4((o4[0]-m4)*i4, (o4[1]-m4)*i4, (o4[2]-m4)*i4, (o4[3]-m4)*i4);
    c5[i]  = make_float4((o5[0]-m5)*i5, (o5[1]-m5)*i5, (o5[2]-m5)*i5, (o5[3]-m5)*i5);
}

// ---- normalize ch0 (from raw), ch1, ch2 --------------------------------------
__global__ __launch_bounds__(256) void norm_abc(const float4* __restrict__ raw,
        const uint2* __restrict__ ch1h, const uint2* __restrict__ ch2h,
        float4* __restrict__ out, const double* __restrict__ slots, int useH) {
    __shared__ double fin[6];
    fold_slots(slots, 0, 6, fin);
    int i = blockIdx.x * 256 + threadIdx.x;        // < 3*V4
    int c = i / V4;
    int ii = i - c * V4;
    float m, inv;
    mean_inv2(fin[2 * c], fin[2 * c + 1], m, inv);
    float4 v;
    if (c == 0)     v = raw[ii];
    else if (useH)  v = unpack_h4((c == 1 ? ch1h : ch2h)[ii]);
    else            v = out[(size_t)c * V4 + ii];
    v.x = (v.x - m) * inv;
    v.y = (v.y - m) * inv;
    v.z = (v.z - m) * inv;
    v.w = (v.w - m) * inv;
    out[(size_t)c * V4 + ii] = v;
}

// ---- host: Gaussian weights ------------------------------------------------
static void gauss_w(double sigma, float* w13, int center) {
    int ks = (int)(4.0 * sigma + 1.0);
    if (ks % 2 == 0) ks++;
    double tmp[13], sum = 0.0;
    for (int i = 0; i < ks; ++i) {
        double x = (double)(i - ks / 2);
        tmp[i] = exp(-0.5 * x * x / (sigma * sigma));
        sum += tmp[i];
    }
    for (int i = 0; i < 13; ++i) w13[i] = 0.f;
    int h = ks / 2;
    for (int i = 0; i < ks; ++i) w13[center + (i - h)] = (float)(tmp[i] / sum);
}

extern "C" void kernel_launch(void* const* d_in, const int* in_sizes, int n_in,
                              void* d_out, int out_size, void* d_ws, size_t ws_size,
                              hipStream_t stream) {
    const float* raw = (const float*)d_in[0];
    float* out = (float*)d_out;
    float* o[6];
    for (int c = 0; c < 6; ++c) o[c] = out + (size_t)c * V;
    double* slots = (double*)d_ws;                  // 12 * 64 doubles

    // optional fp16 staging of pre-norm ch1/ch2 in workspace
    size_t stage_off = 8192;
    size_t stage_need = stage_off + 2 * (size_t)V4 * sizeof(uint2);  // ~28.3 MB
    int useH = (ws_size >= stage_need) ? 1 : 0;
    uint2* ch1h = (uint2*)((char*)d_ws + stage_off);
    uint2* ch2h = ch1h + V4;

    // weights (each centered at its own KS/2)
    ZW zw;
    gauss_w(1.0, zw.w10, 6); gauss_w(1.5, zw.w15, 6);
    gauss_w(2.0, zw.w20, 6); gauss_w(3.0, zw.w30, 6);
    W2 wyA; gauss_w(1.0, wyA.wA, 2);  gauss_w(1.5, wyA.wB, 3);   // KY 5, 7
    W2 wxA; gauss_w(1.0, wxA.wA, 2);  gauss_w(1.5, wxA.wB, 3);   // KX 5, 7
    W2 wyB; gauss_w(2.0, wyB.wA, 4);  gauss_w(3.0, wyB.wB, 6);   // KY 9, 13
    W2 wxB; gauss_w(2.0, wxB.wA, 4);  gauss_w(3.0, wxB.wB, 6);   // KX 9, 13

    const float4* raw4 = (const float4*)raw;
    dim3 blk(256);
    int g4blocks = V4 / 256;                 // 6912
    int zblocks  = V4 / (ZB * 256);          // 1728

    // intermediate placement:
    //   g10z (fp32)  -> o5
    //   g15z (fp16)  -> o3 lower half
    //   g20z (fp16)  -> o3 upper half
    //   g30z (fp16)  -> o4 lower half
    float4* g10z = (float4*)o[5];
    uint2*  g15z = (uint2*)o[3];
    uint2*  g20z = (uint2*)o[3] + V4;
    uint2*  g30z = (uint2*)o[4];

    // zero the stat slots (own kernel; graph-captured memset was ~100 us)
    zero_slots<<<3, blk, 0, stream>>>(slots);
    // z-pass (all sigmas, ZB z per thread) + ch0 stats
    zpass4<<<zblocks, blk, 0, stream>>>(raw4, g10z, g15z, g20z, g30z, zw, slots);
    // merged y+x for both sigma pairs (LDS-staged y-conv)
    yx_both<<<2 * YXB, blk, 0, stream>>>(g10z, g15z, g20z, g30z,
        (float4*)o[0], (float4*)o[1], (float4*)o[2], ch1h, ch2h, useH,
        wyA, wxA, wyB, wxB, slots);
    // ch3/4/5 statistics from G10 (o0), no writes
    deriv_stats<<<g4blocks, blk, 0, stream>>>((const float4*)o[0], o[0], slots);
    // recompute derivatives of G10 -> write normalized ch3(o3), ch4(o4), ch5(o5)
    norm_deriv<<<g4blocks, blk, 0, stream>>>((const float4*)o[0], o[0],
        (float4*)o[3], (float4*)o[4], (float4*)o[5], slots);
    // normalize ch0 (from raw) -> o0, ch1 -> o1, ch2 -> o2
    norm_abc<<<(3 * V4) / 256, blk, 0, stream>>>(raw4, ch1h, ch2h,
        (float4*)out, slots, useH);
}